// Round 3
// baseline (98.717 us; speedup 1.0000x reference)
//
#include <hip/hip_runtime.h>

// Live dataflow of the reference (everything else is dead code — the
// reference pools the INPUT features x, never h):
//   x[i]      = emb_weight[global_idx[i]] + acts[i] @ pe_W + pe_b      [N,256]
//   pooled[g] = sum_{batch[i]==g} x[i]                                 [64,256]
//   z         = relu(pooled @ fc1_W + fc1_b)                           [64,512]
//   out       = log_softmax(z @ fc2_W + fc2_b)                         [64,978]

#define NNODES  100000
#define NGRAPHS 64
#define DIM     256
#define HID     512
#define NOUT    978
#define NPW     16      // nodes per wave in pool_k

// ---------------------------------------------------------------------------
// Kernel 1: fused embed + positional-linear + segment-sum pool.
// One wave handles NPW contiguous nodes; lane owns columns [4*lane, 4*lane+4).
// batch is sorted, so the running accumulator flushes (atomicAdd) only on
// graph boundaries — the boundary test is wave-uniform (scalar branch).
// ---------------------------------------------------------------------------
__global__ __launch_bounds__(256) void pool_k(
    const int* __restrict__ gidx, const float* __restrict__ acts,
    const int* __restrict__ batch, const float* __restrict__ emb,
    const float* __restrict__ peW, const float* __restrict__ peb,
    float* __restrict__ pooled)
{
    const int wave = blockIdx.x * 4 + (threadIdx.x >> 6);
    const int lane = threadIdx.x & 63;
    const int start = wave * NPW;
    if (start >= NNODES) return;
    const int end = min(start + NPW, NNODES);

    // per-lane slice of pe_W rows and pe_b (hoisted out of the node loop)
    const float4 w0 = ((const float4*)peW)[lane];
    const float4 w1 = ((const float4*)(peW + DIM))[lane];
    const float4 bb = ((const float4*)peb)[lane];

    float4 acc = make_float4(0.f, 0.f, 0.f, 0.f);
    int cur = batch[start];

    for (int i = start; i < end; ++i) {
        const int g = batch[i];            // wave-uniform
        if (g != cur) {                    // wave-uniform branch (sorted batch)
            float* p = pooled + (size_t)cur * DIM + lane * 4;
            atomicAdd(p + 0, acc.x); atomicAdd(p + 1, acc.y);
            atomicAdd(p + 2, acc.z); atomicAdd(p + 3, acc.w);
            acc = make_float4(0.f, 0.f, 0.f, 0.f);
            cur = g;
        }
        const int pr = gidx[i];
        const float2 a = ((const float2*)acts)[i];
        const float4 e = ((const float4*)(emb + (size_t)pr * DIM))[lane];
        acc.x += e.x + fmaf(a.x, w0.x, fmaf(a.y, w1.x, bb.x));
        acc.y += e.y + fmaf(a.x, w0.y, fmaf(a.y, w1.y, bb.y));
        acc.z += e.z + fmaf(a.x, w0.z, fmaf(a.y, w1.z, bb.z));
        acc.w += e.w + fmaf(a.x, w0.w, fmaf(a.y, w1.w, bb.w));
    }
    float* p = pooled + (size_t)cur * DIM + lane * 4;
    atomicAdd(p + 0, acc.x); atomicAdd(p + 1, acc.y);
    atomicAdd(p + 2, acc.z); atomicAdd(p + 3, acc.w);
}

// ---------------------------------------------------------------------------
// Kernel 2: z = relu(pooled @ fc1_W + fc1_b).  One block per graph row.
// pooled row staged in LDS (broadcast reads -> conflict-free); W reads
// coalesced across the 512 threads.
// ---------------------------------------------------------------------------
__global__ __launch_bounds__(512) void fc1_k(
    const float* __restrict__ pooled, const float* __restrict__ W,
    const float* __restrict__ bias, float* __restrict__ z)
{
    __shared__ float xs[DIM];
    const int g = blockIdx.x;
    const int j = threadIdx.x;           // 0..511
    if (j < DIM) xs[j] = pooled[g * DIM + j];
    __syncthreads();

    float acc = bias[j];
#pragma unroll 8
    for (int d = 0; d < DIM; ++d)
        acc = fmaf(xs[d], W[d * HID + j], acc);
    z[g * HID + j] = fmaxf(acc, 0.f);
}

// ---------------------------------------------------------------------------
// Kernel 3a: raw logits = z @ fc2_W + fc2_b, written straight into d_out.
// Grid (4, 64): blockIdx.x tiles the 978 outputs, blockIdx.y = graph.
// ---------------------------------------------------------------------------
__global__ __launch_bounds__(256) void fc2_k(
    const float* __restrict__ z, const float* __restrict__ W,
    const float* __restrict__ bias, float* __restrict__ out)
{
    __shared__ float zs[HID];
    const int g = blockIdx.y;
    const int j = blockIdx.x * 256 + threadIdx.x;
    zs[threadIdx.x]       = z[g * HID + threadIdx.x];
    zs[threadIdx.x + 256] = z[g * HID + threadIdx.x + 256];
    __syncthreads();
    if (j >= NOUT) return;

    float acc = bias[j];
#pragma unroll 8
    for (int d = 0; d < HID; ++d)
        acc = fmaf(zs[d], W[d * NOUT + j], acc);
    out[(size_t)g * NOUT + j] = acc;
}

// ---------------------------------------------------------------------------
// Kernel 3b: in-place row log-softmax.  One block (4 waves) per graph row.
// ---------------------------------------------------------------------------
__global__ __launch_bounds__(256) void lsm_k(float* __restrict__ out)
{
    __shared__ float red[8];
    const int g = blockIdx.x;
    float* row = out + (size_t)g * NOUT;
    const int tid  = threadIdx.x;
    const int wid  = tid >> 6;
    const int lane = tid & 63;

    float v[4];
    float m = -INFINITY;
#pragma unroll
    for (int k = 0; k < 4; ++k) {
        const int j = tid + k * 256;
        v[k] = (j < NOUT) ? row[j] : -INFINITY;
        m = fmaxf(m, v[k]);
    }
#pragma unroll
    for (int off = 32; off > 0; off >>= 1) m = fmaxf(m, __shfl_xor(m, off));
    if (lane == 0) red[wid] = m;
    __syncthreads();
    m = fmaxf(fmaxf(red[0], red[1]), fmaxf(red[2], red[3]));

    float s = 0.f;
#pragma unroll
    for (int k = 0; k < 4; ++k) {
        const int j = tid + k * 256;
        if (j < NOUT) s += expf(v[k] - m);
    }
#pragma unroll
    for (int off = 32; off > 0; off >>= 1) s += __shfl_xor(s, off);
    if (lane == 0) red[4 + wid] = s;
    __syncthreads();
    s = red[4] + red[5] + red[6] + red[7];

    const float lse = m + logf(s);
#pragma unroll
    for (int k = 0; k < 4; ++k) {
        const int j = tid + k * 256;
        if (j < NOUT) row[j] = v[k] - lse;
    }
}

// ---------------------------------------------------------------------------
extern "C" void kernel_launch(void* const* d_in, const int* in_sizes, int n_in,
                              void* d_out, int out_size, void* d_ws, size_t ws_size,
                              hipStream_t stream)
{
    // setup_inputs() dict order
    const int*   gidx  = (const int*)  d_in[0];   // global_idx  [N]
    const float* acts  = (const float*)d_in[1];   // acts        [N,2]
    const int*   batch = (const int*)  d_in[4];   // batch       [N] (sorted)
    const float* emb   = (const float*)d_in[5];   // emb_weight  [20000,256]
    const float* peW   = (const float*)d_in[6];   // pe_W        [2,256]
    const float* peb   = (const float*)d_in[7];   // pe_b        [256]
    const float* fc1W  = (const float*)d_in[19];  // fc1_W       [256,512]
    const float* fc1b  = (const float*)d_in[20];  // fc1_b       [512]
    const float* fc2W  = (const float*)d_in[21];  // fc2_W       [512,978]
    const float* fc2b  = (const float*)d_in[22];  // fc2_b       [978]
    // d_in[2,3,8..18] (edge_index, sign, cg_*, gat_*, bn_*, prelu) are dead
    // code w.r.t. the reference output (it pools x, not h).

    float* pooled = (float*)d_ws;                 // 64*256 f32 = 64 KB
    float* z      = pooled + NGRAPHS * DIM;       // 64*512 f32 = 128 KB
    float* out    = (float*)d_out;                // 64*978 f32

    // pooled is accumulated with atomics -> must be zeroed every call
    hipMemsetAsync(pooled, 0, NGRAPHS * DIM * sizeof(float), stream);

    const int waves  = (NNODES + NPW - 1) / NPW;  // 6250
    const int blocks = (waves + 3) / 4;           // 1563
    pool_k<<<blocks, 256, 0, stream>>>(gidx, acts, batch, emb, peW, peb, pooled);
    fc1_k<<<NGRAPHS, 512, 0, stream>>>(pooled, fc1W, fc1b, z);
    fc2_k<<<dim3(4, NGRAPHS), 256, 0, stream>>>(z, fc2W, fc2b, out);
    lsm_k<<<NGRAPHS, 256, 0, stream>>>(out);
}

// Round 4
// 74.197 us; speedup vs baseline: 1.3305x; 1.3305x over previous
//
#include <hip/hip_runtime.h>

// Live dataflow of the reference (everything else is dead code — the
// reference pools the INPUT features x, never h):
//   x[i]      = emb_weight[global_idx[i]] + acts[i] @ pe_W + pe_b      [N,256]
//   pooled[g] = sum_{batch[i]==g} x[i]                                 [64,256]
//   z         = relu(pooled @ fc1_W + fc1_b)                           [64,512]
//   out       = log_softmax(z @ fc2_W + fc2_b)                         [64,978]

#define NNODES  100000
#define NGRAPHS 64
#define DIM     256
#define HID     512
#define NOUT    978
#define NPW     32      // nodes per wave in pool_k (100000/32 = 3125 waves)

// ---------------------------------------------------------------------------
// Kernel 1: fused embed + positional-linear + segment-sum pool.
// One wave handles NPW contiguous nodes, lane owns columns [4*lane,4*lane+4).
// 8-deep gather pipeline: all 8 emb float4 loads issued before any use.
// pe contribution folded into the flush via (sum acts, count) — so the hot
// loop is pure adds. batch sorted -> boundary branch wave-uniform and rare;
// one 4KB atomic flush per wave (plus rare boundary flushes).
// ---------------------------------------------------------------------------
__global__ __launch_bounds__(256) void pool_k(
    const int* __restrict__ gidx, const float* __restrict__ acts,
    const int* __restrict__ batch, const float* __restrict__ emb,
    const float* __restrict__ peW, const float* __restrict__ peb,
    float* __restrict__ pooled)
{
    const int wave = blockIdx.x * 4 + (threadIdx.x >> 6);
    const int lane = threadIdx.x & 63;
    const int start = wave * NPW;
    if (start >= NNODES) return;

    const float4 w0 = ((const float4*)peW)[lane];          // pe_W row 0 slice
    const float4 w1 = ((const float4*)(peW + DIM))[lane];  // pe_W row 1 slice
    const float4 pb = ((const float4*)peb)[lane];          // pe_b slice

    float4 acc  = make_float4(0.f, 0.f, 0.f, 0.f);
    float2 asum = make_float2(0.f, 0.f);
    float  cnt  = 0.f;
    int cur = batch[start];

    auto flush = [&]() {
        float* p = pooled + (size_t)cur * DIM + lane * 4;
        atomicAdd(p + 0, acc.x + asum.x * w0.x + asum.y * w1.x + cnt * pb.x);
        atomicAdd(p + 1, acc.y + asum.x * w0.y + asum.y * w1.y + cnt * pb.y);
        atomicAdd(p + 2, acc.z + asum.x * w0.z + asum.y * w1.z + cnt * pb.z);
        atomicAdd(p + 3, acc.w + asum.x * w0.w + asum.y * w1.w + cnt * pb.w);
        acc = make_float4(0.f, 0.f, 0.f, 0.f);
        asum = make_float2(0.f, 0.f);
        cnt = 0.f;
    };

    #pragma unroll
    for (int t = 0; t < NPW / 8; ++t) {
        const int i = start + t * 8;
        // uniform metadata for 8 nodes (vectorized; i % 8 == 0 -> aligned)
        const int4 b0 = *(const int4*)(batch + i);
        const int4 b1 = *(const int4*)(batch + i + 4);
        const int4 p0 = *(const int4*)(gidx + i);
        const int4 p1 = *(const int4*)(gidx + i + 4);
        const float4 a0 = *(const float4*)(acts + 2 * i);       // nodes i,i+1
        const float4 a1 = *(const float4*)(acts + 2 * i + 4);   // i+2,i+3
        const float4 a2 = *(const float4*)(acts + 2 * i + 8);   // i+4,i+5
        const float4 a3 = *(const float4*)(acts + 2 * i + 12);  // i+6,i+7
        // 8 outstanding 1KB row gathers
        const float4 e0 = *(const float4*)(emb + ((size_t)p0.x << 8) + lane * 4);
        const float4 e1 = *(const float4*)(emb + ((size_t)p0.y << 8) + lane * 4);
        const float4 e2 = *(const float4*)(emb + ((size_t)p0.z << 8) + lane * 4);
        const float4 e3 = *(const float4*)(emb + ((size_t)p0.w << 8) + lane * 4);
        const float4 e4 = *(const float4*)(emb + ((size_t)p1.x << 8) + lane * 4);
        const float4 e5 = *(const float4*)(emb + ((size_t)p1.y << 8) + lane * 4);
        const float4 e6 = *(const float4*)(emb + ((size_t)p1.z << 8) + lane * 4);
        const float4 e7 = *(const float4*)(emb + ((size_t)p1.w << 8) + lane * 4);

        if (b1.w == cur) {
            // sorted batch: batch[i+7]==cur implies all 8 == cur (fast path)
            acc.x += (e0.x + e1.x) + (e2.x + e3.x) + (e4.x + e5.x) + (e6.x + e7.x);
            acc.y += (e0.y + e1.y) + (e2.y + e3.y) + (e4.y + e5.y) + (e6.y + e7.y);
            acc.z += (e0.z + e1.z) + (e2.z + e3.z) + (e4.z + e5.z) + (e6.z + e7.z);
            acc.w += (e0.w + e1.w) + (e2.w + e3.w) + (e4.w + e5.w) + (e6.w + e7.w);
            asum.x += (a0.x + a0.z) + (a1.x + a1.z) + (a2.x + a2.z) + (a3.x + a3.z);
            asum.y += (a0.y + a0.w) + (a1.y + a1.w) + (a2.y + a2.w) + (a3.y + a3.w);
            cnt += 8.f;
        } else {
            // graph boundary inside this 8-group (rare, wave-uniform)
#define NODE(B, E, AX, AY) do {                                   \
            if ((B) != cur) { flush(); cur = (B); }               \
            acc.x += (E).x; acc.y += (E).y;                       \
            acc.z += (E).z; acc.w += (E).w;                       \
            asum.x += (AX); asum.y += (AY); cnt += 1.f; } while (0)
            NODE(b0.x, e0, a0.x, a0.y);
            NODE(b0.y, e1, a0.z, a0.w);
            NODE(b0.z, e2, a1.x, a1.y);
            NODE(b0.w, e3, a1.z, a1.w);
            NODE(b1.x, e4, a2.x, a2.y);
            NODE(b1.y, e5, a2.z, a2.w);
            NODE(b1.z, e6, a3.x, a3.y);
            NODE(b1.w, e7, a3.z, a3.w);
#undef NODE
        }
    }
    flush();
}

// ---------------------------------------------------------------------------
// Kernel 2: z = relu(pooled @ fc1_W + fc1_b).  Grid (2 col-tiles, 64 graphs),
// block 256.  pooled row in LDS (float4 broadcast reads), W coalesced, 16
// outstanding W loads via chunk-4 + unroll-4.
// ---------------------------------------------------------------------------
__global__ __launch_bounds__(256) void fc1_k(
    const float* __restrict__ pooled, const float* __restrict__ W,
    const float* __restrict__ bias, float* __restrict__ z)
{
    __shared__ float xs[DIM];
    const int g = blockIdx.y;
    const int j = blockIdx.x * 256 + threadIdx.x;
    xs[threadIdx.x] = pooled[g * DIM + threadIdx.x];
    __syncthreads();

    float acc = bias[j];
#pragma unroll 4
    for (int d = 0; d < DIM; d += 4) {
        const float4 x4 = *(const float4*)(xs + d);
        acc = fmaf(x4.x, W[(d + 0) * HID + j], acc);
        acc = fmaf(x4.y, W[(d + 1) * HID + j], acc);
        acc = fmaf(x4.z, W[(d + 2) * HID + j], acc);
        acc = fmaf(x4.w, W[(d + 3) * HID + j], acc);
    }
    z[g * HID + j] = fmaxf(acc, 0.f);
}

// ---------------------------------------------------------------------------
// Kernel 3a: logits = z @ fc2_W + fc2_b into d_out.  Grid (4 col-tiles,
// 32 graph-pairs), block 256: each W column load feeds TWO graphs' FMAs
// (halves L2 W traffic, doubles ILP).
// ---------------------------------------------------------------------------
__global__ __launch_bounds__(256) void fc2_k(
    const float* __restrict__ z, const float* __restrict__ W,
    const float* __restrict__ bias, float* __restrict__ out)
{
    __shared__ float zs[2 * HID];
    const int g0 = blockIdx.y * 2;
    const int j = blockIdx.x * 256 + threadIdx.x;
#pragma unroll
    for (int k = 0; k < 4; ++k) {
        const int idx = threadIdx.x + k * 256;        // 0..1023
        zs[idx] = z[g0 * HID + idx];                  // rows g0, g0+1
    }
    __syncthreads();
    if (j >= NOUT) return;

    float acc0 = bias[j], acc1 = acc0;
#pragma unroll 2
    for (int d = 0; d < HID; d += 4) {
        const float4 za = *(const float4*)(zs + d);
        const float4 zb = *(const float4*)(zs + HID + d);
        const float wa = W[(d + 0) * NOUT + j];
        const float wb = W[(d + 1) * NOUT + j];
        const float wc = W[(d + 2) * NOUT + j];
        const float wd = W[(d + 3) * NOUT + j];
        acc0 = fmaf(za.x, wa, acc0); acc1 = fmaf(zb.x, wa, acc1);
        acc0 = fmaf(za.y, wb, acc0); acc1 = fmaf(zb.y, wb, acc1);
        acc0 = fmaf(za.z, wc, acc0); acc1 = fmaf(zb.z, wc, acc1);
        acc0 = fmaf(za.w, wd, acc0); acc1 = fmaf(zb.w, wd, acc1);
    }
    out[(size_t)g0 * NOUT + j]       = acc0;
    out[(size_t)(g0 + 1) * NOUT + j] = acc1;
}

// ---------------------------------------------------------------------------
// Kernel 3b: in-place row log-softmax.  One block (4 waves) per graph row.
// ---------------------------------------------------------------------------
__global__ __launch_bounds__(256) void lsm_k(float* __restrict__ out)
{
    __shared__ float red[8];
    const int g = blockIdx.x;
    float* row = out + (size_t)g * NOUT;
    const int tid  = threadIdx.x;
    const int wid  = tid >> 6;
    const int lane = tid & 63;

    float v[4];
    float m = -INFINITY;
#pragma unroll
    for (int k = 0; k < 4; ++k) {
        const int j = tid + k * 256;
        v[k] = (j < NOUT) ? row[j] : -INFINITY;
        m = fmaxf(m, v[k]);
    }
#pragma unroll
    for (int off = 32; off > 0; off >>= 1) m = fmaxf(m, __shfl_xor(m, off));
    if (lane == 0) red[wid] = m;
    __syncthreads();
    m = fmaxf(fmaxf(red[0], red[1]), fmaxf(red[2], red[3]));

    float s = 0.f;
#pragma unroll
    for (int k = 0; k < 4; ++k) {
        const int j = tid + k * 256;
        if (j < NOUT) s += expf(v[k] - m);
    }
#pragma unroll
    for (int off = 32; off > 0; off >>= 1) s += __shfl_xor(s, off);
    if (lane == 0) red[4 + wid] = s;
    __syncthreads();
    s = red[4] + red[5] + red[6] + red[7];

    const float lse = m + logf(s);
#pragma unroll
    for (int k = 0; k < 4; ++k) {
        const int j = tid + k * 256;
        if (j < NOUT) row[j] = v[k] - lse;
    }
}

// ---------------------------------------------------------------------------
extern "C" void kernel_launch(void* const* d_in, const int* in_sizes, int n_in,
                              void* d_out, int out_size, void* d_ws, size_t ws_size,
                              hipStream_t stream)
{
    // setup_inputs() dict order
    const int*   gidx  = (const int*)  d_in[0];   // global_idx  [N]
    const float* acts  = (const float*)d_in[1];   // acts        [N,2]
    const int*   batch = (const int*)  d_in[4];   // batch       [N] (sorted)
    const float* emb   = (const float*)d_in[5];   // emb_weight  [20000,256]
    const float* peW   = (const float*)d_in[6];   // pe_W        [2,256]
    const float* peb   = (const float*)d_in[7];   // pe_b        [256]
    const float* fc1W  = (const float*)d_in[19];  // fc1_W       [256,512]
    const float* fc1b  = (const float*)d_in[20];  // fc1_b       [512]
    const float* fc2W  = (const float*)d_in[21];  // fc2_W       [512,978]
    const float* fc2b  = (const float*)d_in[22];  // fc2_b       [978]
    // d_in[2,3,8..18] (edge_index, sign, cg_*, gat_*, bn_*, prelu) are dead
    // code w.r.t. the reference output (it pools x, not h).

    float* pooled = (float*)d_ws;                 // 64*256 f32 = 64 KB
    float* z      = pooled + NGRAPHS * DIM;       // 64*512 f32 = 128 KB

    // pooled is accumulated with atomics -> must be zeroed every call
    hipMemsetAsync(pooled, 0, NGRAPHS * DIM * sizeof(float), stream);

    const int waves  = (NNODES + NPW - 1) / NPW;  // 3125
    const int blocks = (waves + 3) / 4;           // 782
    pool_k<<<blocks, 256, 0, stream>>>(gidx, acts, batch, emb, peW, peb, pooled);
    fc1_k<<<dim3(2, NGRAPHS), 256, 0, stream>>>(pooled, fc1W, fc1b, z);
    fc2_k<<<dim3(4, NGRAPHS / 2), 256, 0, stream>>>(z, fc2W, fc2b, (float*)d_out);
    lsm_k<<<NGRAPHS, 256, 0, stream>>>((float*)d_out);
}